// Round 2
// 370.275 us; speedup vs baseline: 1.0240x; 1.0240x over previous
//
#include <hip/hip_runtime.h>
#include <hip/hip_bf16.h>
#include <stdint.h>
#include <stddef.h>

#define HIDDEN 4096
#define BATCH  4096
#define RANK   4

typedef _Float16 f16;
typedef __attribute__((ext_vector_type(8))) _Float16 half8;
typedef __attribute__((ext_vector_type(4))) float f32x4;
typedef __attribute__((ext_vector_type(8))) unsigned short ushort8;

// global->LDS async copy, 16B per lane. LDS dest is wave-uniform base + lane*16.
#define ASYNC_COPY16(g, l)                                                     \
  __builtin_amdgcn_global_load_lds(                                            \
      (__attribute__((address_space(1))) void*)(g),                            \
      (__attribute__((address_space(3))) void*)(l), 16, 0, 0)

// ---------------------------------------------------------------------------
// x (f32) -> f16, 8 elems/thread
__global__ void cast_f16_kernel(const float* __restrict__ src, f16* __restrict__ dst) {
  size_t i = ((size_t)blockIdx.x * blockDim.x + threadIdx.x) * 8;
  float4 v0 = *(const float4*)(src + i);
  float4 v1 = *(const float4*)(src + i + 4);
  union { f16 h[8]; ushort8 v; } u;
  u.h[0] = (f16)v0.x; u.h[1] = (f16)v0.y; u.h[2] = (f16)v0.z; u.h[3] = (f16)v0.w;
  u.h[4] = (f16)v1.x; u.h[5] = (f16)v1.y; u.h[6] = (f16)v1.z; u.h[7] = (f16)v1.w;
  *(ushort8*)(dst + i) = u.v;
}

// ---------------------------------------------------------------------------
// b_mat [K][N] f32 -> Bt [N][K] f16, 64x64 tile transpose.
// LDS tile[n][k], 128B rows, k-seg (8 f16 = 16B) XOR-swizzled by (n>>2)&7:
//   writes (scalar b16, lanes vary tx = n>>2) spread over 8 bank-groups
//   (was 16-way conflict with the old 160B-stride layout);
//   reads (ushort8) stay 16B-aligned and conflict-free.
__global__ void transpose_cast_kernel(const float* __restrict__ B, f16* __restrict__ Bt) {
  __shared__ __align__(16) f16 tile[64 * 64];
  const int t = threadIdx.x;
  const int bx = blockIdx.x;  // n tile
  const int by = blockIdx.y;  // k tile
  const int tx = t & 15, ty = t >> 4;
  #pragma unroll
  for (int i = 0; i < 4; i++) {
    const int k = ty + i * 16;
    float4 v = *(const float4*)(B + (size_t)(by * 64 + k) * HIDDEN + bx * 64 + tx * 4);
    f16 hv[4];
    hv[0] = (f16)v.x; hv[1] = (f16)v.y; hv[2] = (f16)v.z; hv[3] = (f16)v.w;
    #pragma unroll
    for (int c = 0; c < 4; c++) {
      const int n = tx * 4 + c;
      const int phys = (k >> 3) ^ ((n >> 2) & 7);
      tile[n * 64 + phys * 8 + (k & 7)] = hv[c];
    }
  }
  __syncthreads();
  const int wx = t & 7, wy = t >> 3;
  #pragma unroll
  for (int i = 0; i < 2; i++) {
    const int n = wy + i * 32;
    const int phys = wx ^ ((n >> 2) & 7);
    ushort8 v = *(ushort8*)&tile[n * 64 + phys * 8];
    *(ushort8*)(Bt + (size_t)(bx * 64 + n) * HIDDEN + by * 64 + wx * 8) = v;
  }
}

// ---------------------------------------------------------------------------
// hq[b][r] = sum_k h[b][k] * q[k][r]   (f32)
__global__ void hq_kernel(const float* __restrict__ h, const float* __restrict__ q,
                          float* __restrict__ hq) {
  const int b = blockIdx.x;
  const float* hrow = h + (size_t)b * HIDDEN;
  float a0 = 0.f, a1 = 0.f, a2 = 0.f, a3 = 0.f;
  for (int k = threadIdx.x; k < HIDDEN; k += 256) {
    float hv = hrow[k];
    float4 qv = *(const float4*)(q + (size_t)k * RANK);
    a0 += hv * qv.x; a1 += hv * qv.y; a2 += hv * qv.z; a3 += hv * qv.w;
  }
  #pragma unroll
  for (int off = 32; off; off >>= 1) {
    a0 += __shfl_down(a0, off, 64);
    a1 += __shfl_down(a1, off, 64);
    a2 += __shfl_down(a2, off, 64);
    a3 += __shfl_down(a3, off, 64);
  }
  __shared__ float red[4][4];
  const int wave = threadIdx.x >> 6, lane = threadIdx.x & 63;
  if (lane == 0) { red[wave][0] = a0; red[wave][1] = a1; red[wave][2] = a2; red[wave][3] = a3; }
  __syncthreads();
  if (threadIdx.x < 4) {
    float s = red[0][threadIdx.x] + red[1][threadIdx.x] + red[2][threadIdx.x] + red[3][threadIdx.x];
    hq[(size_t)b * RANK + threadIdx.x] = s;
  }
}

// ---------------------------------------------------------------------------
// Main GEMM: out = Xb(f16) @ Bt(f16)^T + h*(1+a) + hq @ p^T, f32 out.
// 256x256x64 tile, 8 waves (2M x 4N), each wave 8x4 MFMA 16x16x32 frags.
// Double-buffered LDS (2 x 64KB), 4 phases per K-tile:
//   phase = { ds_read subtile ; (p0 only: issue 8 global_load_lds for tile
//   t+1 into the other buffer) ; s_barrier ; setprio(1) ; 16 MFMA ;
//   setprio(0) ; s_barrier }, and ONE s_waitcnt vmcnt(0) per K-tile at
//   phase 3's end (loads were issued 4 phases earlier -> latency hidden).
// LDS layout [row][k], 128B rows = 8 segs; physical seg = global ^ (row&7)
// applied at the staging SOURCE (global_load_lds dest must stay linear);
// fragment ds_read_b128 then hits 8 distinct bank-groups -> conflict-free.
#define GBM 256
#define GBN 256
#define GBK 64

#define BARRIER()                                   \
  do {                                              \
    asm volatile("" ::: "memory");                  \
    __builtin_amdgcn_s_barrier();                   \
    asm volatile("" ::: "memory");                  \
  } while (0)

#define VMWAIT0() asm volatile("s_waitcnt vmcnt(0)" ::: "memory")

#define STAGE_TILE(SBUF)                                                     \
  do {                                                                       \
    char* ad_ = (char*)(&As[SBUF][0]) + wave * 1024;                         \
    char* bd_ = (char*)(&Bs[SBUF][0]) + wave * 1024;                         \
    ASYNC_COPY16(ag + (size_t)0 * 64 * HIDDEN, ad_ + 0 * 8192);              \
    ASYNC_COPY16(bg + (size_t)0 * 64 * HIDDEN, bd_ + 0 * 8192);              \
    ASYNC_COPY16(ag + (size_t)1 * 64 * HIDDEN, ad_ + 1 * 8192);              \
    ASYNC_COPY16(bg + (size_t)1 * 64 * HIDDEN, bd_ + 1 * 8192);              \
    ASYNC_COPY16(ag + (size_t)2 * 64 * HIDDEN, ad_ + 2 * 8192);              \
    ASYNC_COPY16(bg + (size_t)2 * 64 * HIDDEN, bd_ + 2 * 8192);              \
    ASYNC_COPY16(ag + (size_t)3 * 64 * HIDDEN, ad_ + 3 * 8192);              \
    ASYNC_COPY16(bg + (size_t)3 * 64 * HIDDEN, bd_ + 3 * 8192);              \
    ag += GBK; bg += GBK;                                                    \
  } while (0)

#define LDF(base, R16, SG) (*(const half8*)((base) + (R16) * (16 * GBK) + (SG)))

#define MFMA4(I, AF)                                                                    \
  acc[I][0] = __builtin_amdgcn_mfma_f32_16x16x32_f16(AF, bf0, acc[I][0], 0, 0, 0);      \
  acc[I][1] = __builtin_amdgcn_mfma_f32_16x16x32_f16(AF, bf1, acc[I][1], 0, 0, 0);      \
  acc[I][2] = __builtin_amdgcn_mfma_f32_16x16x32_f16(AF, bf2, acc[I][2], 0, 0, 0);      \
  acc[I][3] = __builtin_amdgcn_mfma_f32_16x16x32_f16(AF, bf3, acc[I][3], 0, 0, 0);

#define TILE(BUF, SBUF, DO_STAGE)                                            \
  {                                                                          \
    const f16* Ab_ = &As[BUF][0] + (wm * 128 + fm) * GBK;                    \
    const f16* Bb_ = &Bs[BUF][0] + (wn * 64 + fm) * GBK;                     \
    const int sg0_ = ((0 + q) ^ sw) * 8;                                     \
    const int sg1_ = ((4 + q) ^ sw) * 8;                                     \
    half8 a0, a1, a2, a3, bf0, bf1, bf2, bf3;                                \
    /* phase 0: kk=0, acc rows 0-3 (+ prefetch issue) */                     \
    a0 = LDF(Ab_, 0, sg0_); a1 = LDF(Ab_, 1, sg0_);                          \
    a2 = LDF(Ab_, 2, sg0_); a3 = LDF(Ab_, 3, sg0_);                          \
    bf0 = LDF(Bb_, 0, sg0_); bf1 = LDF(Bb_, 1, sg0_);                        \
    bf2 = LDF(Bb_, 2, sg0_); bf3 = LDF(Bb_, 3, sg0_);                        \
    if (DO_STAGE) STAGE_TILE(SBUF);                                          \
    BARRIER();                                                               \
    __builtin_amdgcn_s_setprio(1);                                           \
    MFMA4(0, a0) MFMA4(1, a1) MFMA4(2, a2) MFMA4(3, a3)                      \
    __builtin_amdgcn_s_setprio(0);                                           \
    BARRIER();                                                               \
    /* phase 1: kk=0, acc rows 4-7 (bf retained) */                          \
    a0 = LDF(Ab_, 4, sg0_); a1 = LDF(Ab_, 5, sg0_);                          \
    a2 = LDF(Ab_, 6, sg0_); a3 = LDF(Ab_, 7, sg0_);                          \
    BARRIER();                                                               \
    __builtin_amdgcn_s_setprio(1);                                           \
    MFMA4(4, a0) MFMA4(5, a1) MFMA4(6, a2) MFMA4(7, a3)                      \
    __builtin_amdgcn_s_setprio(0);                                           \
    BARRIER();                                                               \
    /* phase 2: kk=1, acc rows 0-3 */                                        \
    a0 = LDF(Ab_, 0, sg1_); a1 = LDF(Ab_, 1, sg1_);                          \
    a2 = LDF(Ab_, 2, sg1_); a3 = LDF(Ab_, 3, sg1_);                          \
    bf0 = LDF(Bb_, 0, sg1_); bf1 = LDF(Bb_, 1, sg1_);                        \
    bf2 = LDF(Bb_, 2, sg1_); bf3 = LDF(Bb_, 3, sg1_);                        \
    BARRIER();                                                               \
    __builtin_amdgcn_s_setprio(1);                                           \
    MFMA4(0, a0) MFMA4(1, a1) MFMA4(2, a2) MFMA4(3, a3)                      \
    __builtin_amdgcn_s_setprio(0);                                           \
    BARRIER();                                                               \
    /* phase 3: kk=1, acc rows 4-7, then the single per-tile vm drain */     \
    a0 = LDF(Ab_, 4, sg1_); a1 = LDF(Ab_, 5, sg1_);                          \
    a2 = LDF(Ab_, 6, sg1_); a3 = LDF(Ab_, 7, sg1_);                          \
    BARRIER();                                                               \
    __builtin_amdgcn_s_setprio(1);                                           \
    MFMA4(4, a0) MFMA4(5, a1) MFMA4(6, a2) MFMA4(7, a3)                      \
    __builtin_amdgcn_s_setprio(0);                                           \
    VMWAIT0();                                                               \
    BARRIER();                                                               \
  }

__global__ __launch_bounds__(512, 2) void gemm_fused_kernel(
    const f16* __restrict__ Xb, const f16* __restrict__ Bt,
    const float* __restrict__ h, const float* __restrict__ a_diag,
    const float* __restrict__ p_vec, const float* __restrict__ hq,
    float* __restrict__ out) {
  __shared__ __align__(16) f16 As[2][GBM * GBK];  // 2 x 32 KB
  __shared__ __align__(16) f16 Bs[2][GBN * GBK];  // 2 x 32 KB  (total 128 KB)
  const int tid = threadIdx.x;
  const int bm = blockIdx.x, bn = blockIdx.y;
  const int wave = tid >> 6, lane = tid & 63;
  const int wm = wave >> 2, wn = wave & 3;  // 2 x 4 wave grid

  // staging: thread covers LDS rows (tid>>3)+64*l, physical seg (tid&7);
  // global source seg is XOR-swizzled by the row (involution).
  const int srow = tid >> 3;                          // 0..63
  const int gseg = (tid & 7) ^ (srow & 7);
  const f16* ag = Xb + (size_t)(bm * GBM + srow) * HIDDEN + gseg * 8;
  const f16* bg = Bt + (size_t)(bn * GBN + srow) * HIDDEN + gseg * 8;

  f32x4 acc[8][4];
  #pragma unroll
  for (int i = 0; i < 8; i++)
    #pragma unroll
    for (int j = 0; j < 4; j++)
      acc[i][j] = (f32x4){0.f, 0.f, 0.f, 0.f};

  const int q = lane >> 4;   // k-quad within 16x16x32 fragment
  const int fm = lane & 15;  // m/n index within fragment
  const int sw = fm & 7;     // = (fragment row) & 7

  // prologue: stage tile 0 into buf 0
  STAGE_TILE(0);
  VMWAIT0();
  BARRIER();

  #pragma unroll 1
  for (int kt2 = 0; kt2 < 31; ++kt2) {
    TILE(0, 1, true)
    TILE(1, 0, true)
  }
  TILE(0, 1, true)
  TILE(1, 0, false)

  // epilogue: C/D layout col = lane&15, row = (lane>>4)*4 + reg
  float ad[4];
  float4 pv[4];
  #pragma unroll
  for (int j = 0; j < 4; j++) {
    const int gn = bn * GBN + wn * 64 + j * 16 + fm;
    ad[j] = 1.0f + a_diag[gn];
    pv[j] = *(const float4*)(p_vec + (size_t)gn * RANK);
  }
  #pragma unroll
  for (int i = 0; i < 8; i++) {
    #pragma unroll
    for (int r = 0; r < 4; r++) {
      const size_t gb = (size_t)(bm * GBM + wm * 128 + i * 16 + q * 4 + r);
      const float4 hv = *(const float4*)(hq + gb * RANK);
      const size_t rowoff = gb * HIDDEN + bn * GBN + wn * 64 + fm;
      #pragma unroll
      for (int j = 0; j < 4; j++) {
        const size_t idx = rowoff + j * 16;
        const float hval = __builtin_nontemporal_load(&h[idx]);
        const float v = acc[i][j][r] + hval * ad[j] +
                        hv.x * pv[j].x + hv.y * pv[j].y + hv.z * pv[j].z + hv.w * pv[j].w;
        __builtin_nontemporal_store(v, &out[idx]);
      }
    }
  }
}

// ---------------------------------------------------------------------------
// Fallback (ws too small): straight f32 LDS-tiled GEMM + same epilogue.
__global__ void gemm_f32_fallback_kernel(const float* __restrict__ x, const float* __restrict__ bmat,
                                         const float* __restrict__ h, const float* __restrict__ a_diag,
                                         const float* __restrict__ p_vec, const float* __restrict__ hq,
                                         float* __restrict__ out) {
  __shared__ float As[16][64];
  __shared__ float Bs[16][68];
  const int t = threadIdx.x;
  const int bx = blockIdx.x, by = blockIdx.y;  // bx: n tile, by: m tile
  const int tm = t & 15, tn = t >> 4;
  float acc[4][4] = {{0.f}};
  for (int k0 = 0; k0 < HIDDEN; k0 += 16) {
    #pragma unroll
    for (int l = 0; l < 4; l++) {
      int idx = t + l * 256;
      int r = idx >> 4, k = idx & 15;
      As[k][r] = x[(size_t)(by * 64 + r) * HIDDEN + k0 + k];
      int kb = idx >> 6, nb = idx & 63;
      Bs[kb][nb] = bmat[(size_t)(k0 + kb) * HIDDEN + bx * 64 + nb];
    }
    __syncthreads();
    #pragma unroll
    for (int k = 0; k < 16; k++) {
      float av[4], bv[4];
      #pragma unroll
      for (int ii = 0; ii < 4; ii++) av[ii] = As[k][tm * 4 + ii];
      #pragma unroll
      for (int jj = 0; jj < 4; jj++) bv[jj] = Bs[k][tn * 4 + jj];
      #pragma unroll
      for (int ii = 0; ii < 4; ii++)
        #pragma unroll
        for (int jj = 0; jj < 4; jj++)
          acc[ii][jj] += av[ii] * bv[jj];
    }
    __syncthreads();
  }
  #pragma unroll
  for (int jj = 0; jj < 4; jj++) {
    int gn = bx * 64 + tn * 4 + jj;
    float ad = 1.0f + a_diag[gn];
    float4 pv = *(const float4*)(p_vec + (size_t)gn * RANK);
    #pragma unroll
    for (int ii = 0; ii < 4; ii++) {
      size_t gb = (size_t)(by * 64 + tm * 4 + ii);
      float4 hv = *(const float4*)(hq + gb * RANK);
      size_t idx = gb * HIDDEN + gn;
      out[idx] = acc[ii][jj] + h[idx] * ad +
                 hv.x * pv.x + hv.y * pv.y + hv.z * pv.z + hv.w * pv.w;
    }
  }
}

// ---------------------------------------------------------------------------
extern "C" void kernel_launch(void* const* d_in, const int* in_sizes, int n_in,
                              void* d_out, int out_size, void* d_ws, size_t ws_size,
                              hipStream_t stream) {
  const float* h      = (const float*)d_in[0];
  const float* x      = (const float*)d_in[1];
  const float* a_diag = (const float*)d_in[2];
  const float* p_vec  = (const float*)d_in[3];
  const float* q_vec  = (const float*)d_in[4];
  const float* b_mat  = (const float*)d_in[5];
  float* out = (float*)d_out;

  const size_t nElem = (size_t)BATCH * HIDDEN;
  const size_t hq_bytes = (size_t)BATCH * RANK * sizeof(float);       // 64 KB
  const size_t need = hq_bytes + 2 * nElem * sizeof(f16);             // + Xb + Bt

  float* hq = (float*)d_ws;
  hq_kernel<<<BATCH, 256, 0, stream>>>(h, q_vec, hq);

  if (ws_size >= need) {
    f16* Xb = (f16*)((char*)d_ws + hq_bytes);
    f16* Bt = Xb + nElem;
    cast_f16_kernel<<<nElem / 2048, 256, 0, stream>>>(x, Xb);
    transpose_cast_kernel<<<dim3(HIDDEN / 64, HIDDEN / 64), 256, 0, stream>>>(b_mat, Bt);
    gemm_fused_kernel<<<dim3(BATCH / GBM, HIDDEN / GBN), 512, 0, stream>>>(
        Xb, Bt, h, a_diag, p_vec, hq, out);
  } else {
    gemm_f32_fallback_kernel<<<dim3(HIDDEN / 64, BATCH / 64), 256, 0, stream>>>(
        x, b_mat, h, a_diag, p_vec, hq, out);
  }
}

// Round 3
// 362.133 us; speedup vs baseline: 1.0470x; 1.0225x over previous
//
#include <hip/hip_runtime.h>
#include <hip/hip_bf16.h>
#include <stdint.h>
#include <stddef.h>

#define HIDDEN 4096
#define BATCH  4096
#define RANK   4

typedef _Float16 f16;
typedef __attribute__((ext_vector_type(8))) _Float16 half8;
typedef __attribute__((ext_vector_type(4))) float f32x4;
typedef __attribute__((ext_vector_type(8))) unsigned short ushort8;

// global->LDS async copy, 16B per lane. LDS dest is wave-uniform base + lane*16.
#define ASYNC_COPY16(g, l)                                                     \
  __builtin_amdgcn_global_load_lds(                                            \
      (__attribute__((address_space(1))) void*)(g),                            \
      (__attribute__((address_space(3))) void*)(l), 16, 0, 0)

// ---------------------------------------------------------------------------
// x (f32) -> f16, 8 elems/thread
__global__ void cast_f16_kernel(const float* __restrict__ src, f16* __restrict__ dst) {
  size_t i = ((size_t)blockIdx.x * blockDim.x + threadIdx.x) * 8;
  float4 v0 = *(const float4*)(src + i);
  float4 v1 = *(const float4*)(src + i + 4);
  union { f16 h[8]; ushort8 v; } u;
  u.h[0] = (f16)v0.x; u.h[1] = (f16)v0.y; u.h[2] = (f16)v0.z; u.h[3] = (f16)v0.w;
  u.h[4] = (f16)v1.x; u.h[5] = (f16)v1.y; u.h[6] = (f16)v1.z; u.h[7] = (f16)v1.w;
  *(ushort8*)(dst + i) = u.v;
}

// ---------------------------------------------------------------------------
// b_mat [K][N] f32 -> Bt [N][K] f16, 64x64 tile transpose.
// LDS tile[n][k], 128B rows, k-seg (8 f16 = 16B) XOR-swizzled by (n>>2)&7.
__global__ void transpose_cast_kernel(const float* __restrict__ B, f16* __restrict__ Bt) {
  __shared__ __align__(16) f16 tile[64 * 64];
  const int t = threadIdx.x;
  const int bx = blockIdx.x;  // n tile
  const int by = blockIdx.y;  // k tile
  const int tx = t & 15, ty = t >> 4;
  #pragma unroll
  for (int i = 0; i < 4; i++) {
    const int k = ty + i * 16;
    float4 v = *(const float4*)(B + (size_t)(by * 64 + k) * HIDDEN + bx * 64 + tx * 4);
    f16 hv[4];
    hv[0] = (f16)v.x; hv[1] = (f16)v.y; hv[2] = (f16)v.z; hv[3] = (f16)v.w;
    #pragma unroll
    for (int c = 0; c < 4; c++) {
      const int n = tx * 4 + c;
      const int phys = (k >> 3) ^ ((n >> 2) & 7);
      tile[n * 64 + phys * 8 + (k & 7)] = hv[c];
    }
  }
  __syncthreads();
  const int wx = t & 7, wy = t >> 3;
  #pragma unroll
  for (int i = 0; i < 2; i++) {
    const int n = wy + i * 32;
    const int phys = wx ^ ((n >> 2) & 7);
    ushort8 v = *(ushort8*)&tile[n * 64 + phys * 8];
    *(ushort8*)(Bt + (size_t)(bx * 64 + n) * HIDDEN + by * 64 + wx * 8) = v;
  }
}

// ---------------------------------------------------------------------------
// hq[b][r] = sum_k h[b][k] * q[k][r]   (f32)
__global__ void hq_kernel(const float* __restrict__ h, const float* __restrict__ q,
                          float* __restrict__ hq) {
  const int b = blockIdx.x;
  const float* hrow = h + (size_t)b * HIDDEN;
  float a0 = 0.f, a1 = 0.f, a2 = 0.f, a3 = 0.f;
  for (int k = threadIdx.x; k < HIDDEN; k += 256) {
    float hv = hrow[k];
    float4 qv = *(const float4*)(q + (size_t)k * RANK);
    a0 += hv * qv.x; a1 += hv * qv.y; a2 += hv * qv.z; a3 += hv * qv.w;
  }
  #pragma unroll
  for (int off = 32; off; off >>= 1) {
    a0 += __shfl_down(a0, off, 64);
    a1 += __shfl_down(a1, off, 64);
    a2 += __shfl_down(a2, off, 64);
    a3 += __shfl_down(a3, off, 64);
  }
  __shared__ float red[4][4];
  const int wave = threadIdx.x >> 6, lane = threadIdx.x & 63;
  if (lane == 0) { red[wave][0] = a0; red[wave][1] = a1; red[wave][2] = a2; red[wave][3] = a3; }
  __syncthreads();
  if (threadIdx.x < 4) {
    float s = red[0][threadIdx.x] + red[1][threadIdx.x] + red[2][threadIdx.x] + red[3][threadIdx.x];
    hq[(size_t)b * RANK + threadIdx.x] = s;
  }
}

// ---------------------------------------------------------------------------
// Main GEMM: out = Xb(f16) @ Bt(f16)^T + h*(1+a) + hq @ p^T, f32 out.
// 256x256x64 tile, 8 waves (2M x 4N), 4 phases/K-tile, dbuf LDS.
// T4 counted-vmcnt pipeline: tile t+1's 8 loads split into 4 units issued
// one per phase of tile t, ordered by first consumption:
//   P0: B rows 0-127 | P1: B rows 128-255 | P2: A rows {0-63,128-191}
//   P3: A rows {64-127,192-255}   (A-odd rows read only by phases 1/3)
// Waits (vmcnt retires in order):
//   boundary: vmcnt(2) -> B+A-even of next tile drained, A-odd (2 loads)
//             still in flight; phase 0 doesn't read those rows.
//   after P0: vmcnt(2) -> A-odd drained (2 newer = next-next B unit,
//             targets the other buffer). Phases 1-2: plain barriers.
// Loads never fully drain in steady state (m218 T4: +38% vs drain-0).
#define GBM 256
#define GBN 256
#define GBK 64

#define BARRIER()                                   \
  do {                                              \
    asm volatile("" ::: "memory");                  \
    __builtin_amdgcn_s_barrier();                   \
    asm volatile("" ::: "memory");                  \
  } while (0)

#define VMWAIT0() asm volatile("s_waitcnt vmcnt(0)" ::: "memory")
#define VMWAIT2() asm volatile("s_waitcnt vmcnt(2)" ::: "memory")
#define VMNOP()   do { } while (0)

#define STAGE_B01(SBUF)                                                      \
  do {                                                                       \
    char* bd_ = (char*)(&Bs[SBUF][0]) + wave * 1024;                         \
    ASYNC_COPY16(bg + (size_t)0 * 64 * HIDDEN, bd_ + 0 * 8192);              \
    ASYNC_COPY16(bg + (size_t)1 * 64 * HIDDEN, bd_ + 1 * 8192);              \
  } while (0)
#define STAGE_B23(SBUF)                                                      \
  do {                                                                       \
    char* bd_ = (char*)(&Bs[SBUF][0]) + wave * 1024;                         \
    ASYNC_COPY16(bg + (size_t)2 * 64 * HIDDEN, bd_ + 2 * 8192);              \
    ASYNC_COPY16(bg + (size_t)3 * 64 * HIDDEN, bd_ + 3 * 8192);              \
  } while (0)
#define STAGE_A02(SBUF)                                                      \
  do {                                                                       \
    char* ad_ = (char*)(&As[SBUF][0]) + wave * 1024;                         \
    ASYNC_COPY16(ag + (size_t)0 * 64 * HIDDEN, ad_ + 0 * 8192);              \
    ASYNC_COPY16(ag + (size_t)2 * 64 * HIDDEN, ad_ + 2 * 8192);              \
  } while (0)
#define STAGE_A13(SBUF)                                                      \
  do {                                                                       \
    char* ad_ = (char*)(&As[SBUF][0]) + wave * 1024;                         \
    ASYNC_COPY16(ag + (size_t)1 * 64 * HIDDEN, ad_ + 1 * 8192);              \
    ASYNC_COPY16(ag + (size_t)3 * 64 * HIDDEN, ad_ + 3 * 8192);              \
    ag += GBK; bg += GBK;                                                    \
  } while (0)

#define LDF(base, R16, SG) (*(const half8*)((base) + (R16) * (16 * GBK) + (SG)))

#define MFMA4(I, AF)                                                                    \
  acc[I][0] = __builtin_amdgcn_mfma_f32_16x16x32_f16(AF, bf0, acc[I][0], 0, 0, 0);      \
  acc[I][1] = __builtin_amdgcn_mfma_f32_16x16x32_f16(AF, bf1, acc[I][1], 0, 0, 0);      \
  acc[I][2] = __builtin_amdgcn_mfma_f32_16x16x32_f16(AF, bf2, acc[I][2], 0, 0, 0);      \
  acc[I][3] = __builtin_amdgcn_mfma_f32_16x16x32_f16(AF, bf3, acc[I][3], 0, 0, 0);

// One K-tile. BUF = consumed LDS buffer; SBUF = staged buffer (next tile);
// DO_STAGE compile-time; WAITP0 = wait after phase 0 (vmcnt(2) steady,
// vmcnt(0) last tile); WAITEND = wait at tile end (vmcnt(2) steady, none last).
#define TILE(BUF, SBUF, DO_STAGE, WAITP0, WAITEND)                           \
  {                                                                          \
    const f16* Ab_ = &As[BUF][0] + (wm * 128 + fm) * GBK;                    \
    const f16* Bb_ = &Bs[BUF][0] + (wn * 64 + fm) * GBK;                     \
    const int sg0_ = ((0 + q) ^ sw) * 8;                                     \
    const int sg1_ = ((4 + q) ^ sw) * 8;                                     \
    half8 a0, a1, a2, a3, bf0, bf1, bf2, bf3;                                \
    /* phase 0: kk=0, acc rows 0-3 */                                        \
    a0 = LDF(Ab_, 0, sg0_); a1 = LDF(Ab_, 1, sg0_);                          \
    a2 = LDF(Ab_, 2, sg0_); a3 = LDF(Ab_, 3, sg0_);                          \
    bf0 = LDF(Bb_, 0, sg0_); bf1 = LDF(Bb_, 1, sg0_);                        \
    bf2 = LDF(Bb_, 2, sg0_); bf3 = LDF(Bb_, 3, sg0_);                        \
    if (DO_STAGE) STAGE_B01(SBUF);                                           \
    BARRIER();                                                               \
    __builtin_amdgcn_s_setprio(1);                                           \
    MFMA4(0, a0) MFMA4(1, a1) MFMA4(2, a2) MFMA4(3, a3)                      \
    __builtin_amdgcn_s_setprio(0);                                           \
    WAITP0;                                                                  \
    BARRIER();                                                               \
    /* phase 1: kk=0, acc rows 4-7 (A-odd rows now drained) */               \
    a0 = LDF(Ab_, 4, sg0_); a1 = LDF(Ab_, 5, sg0_);                          \
    a2 = LDF(Ab_, 6, sg0_); a3 = LDF(Ab_, 7, sg0_);                          \
    if (DO_STAGE) STAGE_B23(SBUF);                                           \
    BARRIER();                                                               \
    __builtin_amdgcn_s_setprio(1);                                           \
    MFMA4(4, a0) MFMA4(5, a1) MFMA4(6, a2) MFMA4(7, a3)                      \
    __builtin_amdgcn_s_setprio(0);                                           \
    BARRIER();                                                               \
    /* phase 2: kk=1, acc rows 0-3 */                                        \
    a0 = LDF(Ab_, 0, sg1_); a1 = LDF(Ab_, 1, sg1_);                          \
    a2 = LDF(Ab_, 2, sg1_); a3 = LDF(Ab_, 3, sg1_);                          \
    bf0 = LDF(Bb_, 0, sg1_); bf1 = LDF(Bb_, 1, sg1_);                        \
    bf2 = LDF(Bb_, 2, sg1_); bf3 = LDF(Bb_, 3, sg1_);                        \
    if (DO_STAGE) STAGE_A02(SBUF);                                           \
    BARRIER();                                                               \
    __builtin_amdgcn_s_setprio(1);                                           \
    MFMA4(0, a0) MFMA4(1, a1) MFMA4(2, a2) MFMA4(3, a3)                      \
    __builtin_amdgcn_s_setprio(0);                                           \
    BARRIER();                                                               \
    /* phase 3: kk=1, acc rows 4-7 */                                        \
    a0 = LDF(Ab_, 4, sg1_); a1 = LDF(Ab_, 5, sg1_);                          \
    a2 = LDF(Ab_, 6, sg1_); a3 = LDF(Ab_, 7, sg1_);                          \
    if (DO_STAGE) STAGE_A13(SBUF);                                           \
    BARRIER();                                                               \
    __builtin_amdgcn_s_setprio(1);                                           \
    MFMA4(4, a0) MFMA4(5, a1) MFMA4(6, a2) MFMA4(7, a3)                      \
    __builtin_amdgcn_s_setprio(0);                                           \
    WAITEND;                                                                 \
    BARRIER();                                                               \
  }

__global__ __launch_bounds__(512, 2) void gemm_fused_kernel(
    const f16* __restrict__ Xb, const f16* __restrict__ Bt,
    const float* __restrict__ h, const float* __restrict__ a_diag,
    const float* __restrict__ p_vec, const float* __restrict__ hq,
    float* __restrict__ out) {
  __shared__ __align__(16) f16 As[2][GBM * GBK];  // 2 x 32 KB
  __shared__ __align__(16) f16 Bs[2][GBN * GBK];  // 2 x 32 KB  (total 128 KB)
  const int tid = threadIdx.x;
  const int bm = blockIdx.x, bn = blockIdx.y;
  const int wave = tid >> 6, lane = tid & 63;
  const int wm = wave >> 2, wn = wave & 3;  // 2 x 4 wave grid

  // staging: thread covers LDS rows (tid>>3)+64*l, physical seg (tid&7);
  // global source seg is XOR-swizzled by the row (involution).
  const int srow = tid >> 3;                          // 0..63
  const int gseg = (tid & 7) ^ (srow & 7);
  const f16* ag = Xb + (size_t)(bm * GBM + srow) * HIDDEN + gseg * 8;
  const f16* bg = Bt + (size_t)(bn * GBN + srow) * HIDDEN + gseg * 8;

  f32x4 acc[8][4];
  #pragma unroll
  for (int i = 0; i < 8; i++)
    #pragma unroll
    for (int j = 0; j < 4; j++)
      acc[i][j] = (f32x4){0.f, 0.f, 0.f, 0.f};

  const int q = lane >> 4;   // k-quad within 16x16x32 fragment
  const int fm = lane & 15;  // m/n index within fragment
  const int sw = fm & 7;     // = (fragment row) & 7

  // prologue: stage tile 0 into buf 0 (same unit order as steady state),
  // boundary wait vmcnt(2): B + A-even drained, A-odd in flight.
  STAGE_B01(0); STAGE_B23(0); STAGE_A02(0); STAGE_A13(0);
  VMWAIT2();
  BARRIER();

  // tiles 0..61 (31 dbuf pairs), each stages the next tile
  #pragma unroll 1
  for (int kt2 = 0; kt2 < 31; ++kt2) {
    TILE(0, 1, 1, VMWAIT2(), VMWAIT2())
    TILE(1, 0, 1, VMWAIT2(), VMWAIT2())
  }
  // tile 62: stages tile 63 into buf 1
  TILE(0, 1, 1, VMWAIT2(), VMWAIT2())
  // tile 63: no staging; after P0 must fully drain (no newer loads to count)
  TILE(1, 0, 0, VMWAIT0(), VMNOP())

  // epilogue: C/D layout col = lane&15, row = (lane>>4)*4 + reg
  float ad[4];
  float4 pv[4];
  #pragma unroll
  for (int j = 0; j < 4; j++) {
    const int gn = bn * GBN + wn * 64 + j * 16 + fm;
    ad[j] = 1.0f + a_diag[gn];
    pv[j] = *(const float4*)(p_vec + (size_t)gn * RANK);
  }
  #pragma unroll
  for (int i = 0; i < 8; i++) {
    #pragma unroll
    for (int r = 0; r < 4; r++) {
      const size_t gb = (size_t)(bm * GBM + wm * 128 + i * 16 + q * 4 + r);
      const float4 hv = *(const float4*)(hq + gb * RANK);
      const size_t rowoff = gb * HIDDEN + bn * GBN + wn * 64 + fm;
      #pragma unroll
      for (int j = 0; j < 4; j++) {
        const size_t idx = rowoff + j * 16;
        const float hval = __builtin_nontemporal_load(&h[idx]);
        const float v = acc[i][j][r] + hval * ad[j] +
                        hv.x * pv[j].x + hv.y * pv[j].y + hv.z * pv[j].z + hv.w * pv[j].w;
        __builtin_nontemporal_store(v, &out[idx]);
      }
    }
  }
}

// ---------------------------------------------------------------------------
// Fallback (ws too small): straight f32 LDS-tiled GEMM + same epilogue.
__global__ void gemm_f32_fallback_kernel(const float* __restrict__ x, const float* __restrict__ bmat,
                                         const float* __restrict__ h, const float* __restrict__ a_diag,
                                         const float* __restrict__ p_vec, const float* __restrict__ hq,
                                         float* __restrict__ out) {
  __shared__ float As[16][64];
  __shared__ float Bs[16][68];
  const int t = threadIdx.x;
  const int bx = blockIdx.x, by = blockIdx.y;  // bx: n tile, by: m tile
  const int tm = t & 15, tn = t >> 4;
  float acc[4][4] = {{0.f}};
  for (int k0 = 0; k0 < HIDDEN; k0 += 16) {
    #pragma unroll
    for (int l = 0; l < 4; l++) {
      int idx = t + l * 256;
      int r = idx >> 4, k = idx & 15;
      As[k][r] = x[(size_t)(by * 64 + r) * HIDDEN + k0 + k];
      int kb = idx >> 6, nb = idx & 63;
      Bs[kb][nb] = bmat[(size_t)(k0 + kb) * HIDDEN + bx * 64 + nb];
    }
    __syncthreads();
    #pragma unroll
    for (int k = 0; k < 16; k++) {
      float av[4], bv[4];
      #pragma unroll
      for (int ii = 0; ii < 4; ii++) av[ii] = As[k][tm * 4 + ii];
      #pragma unroll
      for (int jj = 0; jj < 4; jj++) bv[jj] = Bs[k][tn * 4 + jj];
      #pragma unroll
      for (int ii = 0; ii < 4; ii++)
        #pragma unroll
        for (int jj = 0; jj < 4; jj++)
          acc[ii][jj] += av[ii] * bv[jj];
    }
    __syncthreads();
  }
  #pragma unroll
  for (int jj = 0; jj < 4; jj++) {
    int gn = bx * 64 + tn * 4 + jj;
    float ad = 1.0f + a_diag[gn];
    float4 pv = *(const float4*)(p_vec + (size_t)gn * RANK);
    #pragma unroll
    for (int ii = 0; ii < 4; ii++) {
      size_t gb = (size_t)(by * 64 + tm * 4 + ii);
      float4 hv = *(const float4*)(hq + gb * RANK);
      size_t idx = gb * HIDDEN + gn;
      out[idx] = acc[ii][jj] + h[idx] * ad +
                 hv.x * pv.x + hv.y * pv.y + hv.z * pv.z + hv.w * pv.w;
    }
  }
}

// ---------------------------------------------------------------------------
extern "C" void kernel_launch(void* const* d_in, const int* in_sizes, int n_in,
                              void* d_out, int out_size, void* d_ws, size_t ws_size,
                              hipStream_t stream) {
  const float* h      = (const float*)d_in[0];
  const float* x      = (const float*)d_in[1];
  const float* a_diag = (const float*)d_in[2];
  const float* p_vec  = (const float*)d_in[3];
  const float* q_vec  = (const float*)d_in[4];
  const float* b_mat  = (const float*)d_in[5];
  float* out = (float*)d_out;

  const size_t nElem = (size_t)BATCH * HIDDEN;
  const size_t hq_bytes = (size_t)BATCH * RANK * sizeof(float);       // 64 KB
  const size_t need = hq_bytes + 2 * nElem * sizeof(f16);             // + Xb + Bt

  float* hq = (float*)d_ws;
  hq_kernel<<<BATCH, 256, 0, stream>>>(h, q_vec, hq);

  if (ws_size >= need) {
    f16* Xb = (f16*)((char*)d_ws + hq_bytes);
    f16* Bt = Xb + nElem;
    cast_f16_kernel<<<nElem / 2048, 256, 0, stream>>>(x, Xb);
    transpose_cast_kernel<<<dim3(HIDDEN / 64, HIDDEN / 64), 256, 0, stream>>>(b_mat, Bt);
    gemm_fused_kernel<<<dim3(BATCH / GBM, HIDDEN / GBN), 512, 0, stream>>>(
        Xb, Bt, h, a_diag, p_vec, hq, out);
  } else {
    gemm_f32_fallback_kernel<<<dim3(HIDDEN / 64, BATCH / 64), 256, 0, stream>>>(
        x, b_mat, h, a_diag, p_vec, hq, out);
  }
}

// Round 5
// 358.372 us; speedup vs baseline: 1.0580x; 1.0105x over previous
//
#include <hip/hip_runtime.h>
#include <hip/hip_bf16.h>
#include <stdint.h>
#include <stddef.h>

#define HIDDEN 4096
#define BATCH  4096
#define RANK   4

typedef _Float16 f16;
typedef __attribute__((ext_vector_type(8))) _Float16 half8;
typedef __attribute__((ext_vector_type(4))) float f32x4;
typedef __attribute__((ext_vector_type(8))) unsigned short ushort8;

// global->LDS async copy, 16B per lane. LDS dest is wave-uniform base + lane*16.
#define ASYNC_COPY16(g, l)                                                     \
  __builtin_amdgcn_global_load_lds(                                            \
      (__attribute__((address_space(1))) void*)(g),                            \
      (__attribute__((address_space(3))) void*)(l), 16, 0, 0)

// ---------------------------------------------------------------------------
// x (f32) -> f16, 8 elems/thread
__global__ void cast_f16_kernel(const float* __restrict__ src, f16* __restrict__ dst) {
  size_t i = ((size_t)blockIdx.x * blockDim.x + threadIdx.x) * 8;
  float4 v0 = *(const float4*)(src + i);
  float4 v1 = *(const float4*)(src + i + 4);
  union { f16 h[8]; ushort8 v; } u;
  u.h[0] = (f16)v0.x; u.h[1] = (f16)v0.y; u.h[2] = (f16)v0.z; u.h[3] = (f16)v0.w;
  u.h[4] = (f16)v1.x; u.h[5] = (f16)v1.y; u.h[6] = (f16)v1.z; u.h[7] = (f16)v1.w;
  *(ushort8*)(dst + i) = u.v;
}

// ---------------------------------------------------------------------------
// b_mat [K][N] f32 -> Bt [N][K] f16, 64x64 tile transpose.
// LDS tile[n][k], 128B rows, k-seg (8 f16 = 16B) XOR-swizzled by (n>>2)&7.
__global__ void transpose_cast_kernel(const float* __restrict__ B, f16* __restrict__ Bt) {
  __shared__ __align__(16) f16 tile[64 * 64];
  const int t = threadIdx.x;
  const int bx = blockIdx.x;  // n tile
  const int by = blockIdx.y;  // k tile
  const int tx = t & 15, ty = t >> 4;
  #pragma unroll
  for (int i = 0; i < 4; i++) {
    const int k = ty + i * 16;
    float4 v = *(const float4*)(B + (size_t)(by * 64 + k) * HIDDEN + bx * 64 + tx * 4);
    f16 hv[4];
    hv[0] = (f16)v.x; hv[1] = (f16)v.y; hv[2] = (f16)v.z; hv[3] = (f16)v.w;
    #pragma unroll
    for (int c = 0; c < 4; c++) {
      const int n = tx * 4 + c;
      const int phys = (k >> 3) ^ ((n >> 2) & 7);
      tile[n * 64 + phys * 8 + (k & 7)] = hv[c];
    }
  }
  __syncthreads();
  const int wx = t & 7, wy = t >> 3;
  #pragma unroll
  for (int i = 0; i < 2; i++) {
    const int n = wy + i * 32;
    const int phys = wx ^ ((n >> 2) & 7);
    ushort8 v = *(ushort8*)&tile[n * 64 + phys * 8];
    *(ushort8*)(Bt + (size_t)(bx * 64 + n) * HIDDEN + by * 64 + wx * 8) = v;
  }
}

// ---------------------------------------------------------------------------
// hq[b][r] = sum_k h[b][k] * q[k][r]   (f32)
__global__ void hq_kernel(const float* __restrict__ h, const float* __restrict__ q,
                          float* __restrict__ hq) {
  const int b = blockIdx.x;
  const float* hrow = h + (size_t)b * HIDDEN;
  float a0 = 0.f, a1 = 0.f, a2 = 0.f, a3 = 0.f;
  for (int k = threadIdx.x; k < HIDDEN; k += 256) {
    float hv = hrow[k];
    float4 qv = *(const float4*)(q + (size_t)k * RANK);
    a0 += hv * qv.x; a1 += hv * qv.y; a2 += hv * qv.z; a3 += hv * qv.w;
  }
  #pragma unroll
  for (int off = 32; off; off >>= 1) {
    a0 += __shfl_down(a0, off, 64);
    a1 += __shfl_down(a1, off, 64);
    a2 += __shfl_down(a2, off, 64);
    a3 += __shfl_down(a3, off, 64);
  }
  __shared__ float red[4][4];
  const int wave = threadIdx.x >> 6, lane = threadIdx.x & 63;
  if (lane == 0) { red[wave][0] = a0; red[wave][1] = a1; red[wave][2] = a2; red[wave][3] = a3; }
  __syncthreads();
  if (threadIdx.x < 4) {
    float s = red[0][threadIdx.x] + red[1][threadIdx.x] + red[2][threadIdx.x] + red[3][threadIdx.x];
    hq[(size_t)b * RANK + threadIdx.x] = s;
  }
}

// ---------------------------------------------------------------------------
// Main GEMM: out = Xb(f16) @ Bt(f16)^T + h*(1+a) + hq @ p^T, f32 out.
// 256x256x64 tile, 8 waves (2M x 4N), dbuf LDS, ONE barrier per K-tile.
// Software-pipelined fragment reads (1 MFMA-quad lookahead, 2 register
// banks): compiler emits counted lgkmcnt(4/8/4/0) so LDS delivery of quad
// p+1 overlaps the MFMA cluster of quad p (round-3 post-mortem: the
// 2-barrier-per-phase lockstep serialized LDS (~2100cyc) with MFMA
// (~2480cyc) per tile -> 6190 cyc measured; this overlaps them).
// Tile: B1; {R0 issue, STAGE 8, R1 issue}; M0; R2; M1; R3; M2; M3; vmcnt(0).
// Sync proof: every wave's reads of buf(t-1) are delivered before its
// M3(t-1) (lgkm), which precedes B1(t); staging of buf(t+1) (same slot as
// buf(t-1)) starts only after B1(t). Buffer visibility: per-wave vmcnt(0)
// before B1 -> all staging writes visible to all waves after B1.
#define GBM 256
#define GBN 256
#define GBK 64

#define BARRIER()                                   \
  do {                                              \
    asm volatile("" ::: "memory");                  \
    __builtin_amdgcn_s_barrier();                   \
    asm volatile("" ::: "memory");                  \
  } while (0)

#define VMWAIT0() asm volatile("s_waitcnt vmcnt(0)" ::: "memory")
#define SBAR() __builtin_amdgcn_sched_barrier(0)

#define STAGE_ALL(SBUF)                                                      \
  do {                                                                       \
    char* ad_ = (char*)(&As[SBUF][0]) + wave * 1024;                         \
    char* bd_ = (char*)(&Bs[SBUF][0]) + wave * 1024;                         \
    ASYNC_COPY16(bg + (size_t)0 * 64 * HIDDEN, bd_ + 0 * 8192);              \
    ASYNC_COPY16(bg + (size_t)1 * 64 * HIDDEN, bd_ + 1 * 8192);              \
    ASYNC_COPY16(bg + (size_t)2 * 64 * HIDDEN, bd_ + 2 * 8192);              \
    ASYNC_COPY16(bg + (size_t)3 * 64 * HIDDEN, bd_ + 3 * 8192);              \
    ASYNC_COPY16(ag + (size_t)0 * 64 * HIDDEN, ad_ + 0 * 8192);              \
    ASYNC_COPY16(ag + (size_t)1 * 64 * HIDDEN, ad_ + 1 * 8192);              \
    ASYNC_COPY16(ag + (size_t)2 * 64 * HIDDEN, ad_ + 2 * 8192);              \
    ASYNC_COPY16(ag + (size_t)3 * 64 * HIDDEN, ad_ + 3 * 8192);              \
    ag += GBK; bg += GBK;                                                    \
  } while (0)

#define LDF(base, R16, SG) (*(const half8*)((base) + (R16) * (16 * GBK) + (SG)))

// 16 MFMAs: acc rows I0..I0+3 (x4 cols), A-frags AF[0..3], B-frags BF[0..3]
#define MQUAD(I0, AF, BF)                                                               \
  __builtin_amdgcn_s_setprio(1);                                                        \
  acc[I0+0][0] = __builtin_amdgcn_mfma_f32_16x16x32_f16(AF[0], BF[0], acc[I0+0][0], 0, 0, 0); \
  acc[I0+0][1] = __builtin_amdgcn_mfma_f32_16x16x32_f16(AF[0], BF[1], acc[I0+0][1], 0, 0, 0); \
  acc[I0+0][2] = __builtin_amdgcn_mfma_f32_16x16x32_f16(AF[0], BF[2], acc[I0+0][2], 0, 0, 0); \
  acc[I0+0][3] = __builtin_amdgcn_mfma_f32_16x16x32_f16(AF[0], BF[3], acc[I0+0][3], 0, 0, 0); \
  acc[I0+1][0] = __builtin_amdgcn_mfma_f32_16x16x32_f16(AF[1], BF[0], acc[I0+1][0], 0, 0, 0); \
  acc[I0+1][1] = __builtin_amdgcn_mfma_f32_16x16x32_f16(AF[1], BF[1], acc[I0+1][1], 0, 0, 0); \
  acc[I0+1][2] = __builtin_amdgcn_mfma_f32_16x16x32_f16(AF[1], BF[2], acc[I0+1][2], 0, 0, 0); \
  acc[I0+1][3] = __builtin_amdgcn_mfma_f32_16x16x32_f16(AF[1], BF[3], acc[I0+1][3], 0, 0, 0); \
  acc[I0+2][0] = __builtin_amdgcn_mfma_f32_16x16x32_f16(AF[2], BF[0], acc[I0+2][0], 0, 0, 0); \
  acc[I0+2][1] = __builtin_amdgcn_mfma_f32_16x16x32_f16(AF[2], BF[1], acc[I0+2][1], 0, 0, 0); \
  acc[I0+2][2] = __builtin_amdgcn_mfma_f32_16x16x32_f16(AF[2], BF[2], acc[I0+2][2], 0, 0, 0); \
  acc[I0+2][3] = __builtin_amdgcn_mfma_f32_16x16x32_f16(AF[2], BF[3], acc[I0+2][3], 0, 0, 0); \
  acc[I0+3][0] = __builtin_amdgcn_mfma_f32_16x16x32_f16(AF[3], BF[0], acc[I0+3][0], 0, 0, 0); \
  acc[I0+3][1] = __builtin_amdgcn_mfma_f32_16x16x32_f16(AF[3], BF[1], acc[I0+3][1], 0, 0, 0); \
  acc[I0+3][2] = __builtin_amdgcn_mfma_f32_16x16x32_f16(AF[3], BF[2], acc[I0+3][2], 0, 0, 0); \
  acc[I0+3][3] = __builtin_amdgcn_mfma_f32_16x16x32_f16(AF[3], BF[3], acc[I0+3][3], 0, 0, 0); \
  __builtin_amdgcn_s_setprio(0);

// One K-tile. BUF = consumed LDS buffer; SBUF = staged buffer (next tile).
// Read banks: aA/aB alternate (WAR-safe: each rewrite follows the MQUAD
// that consumed the old value in program order). bE = kk0 B-frags, bO = kk1.
#define TILE(BUF, SBUF, DO_STAGE)                                            \
  {                                                                          \
    const f16* Ab_ = &As[BUF][0] + (wm * 128 + fm) * GBK;                    \
    const f16* Bb_ = &Bs[BUF][0] + (wn * 64 + fm) * GBK;                     \
    const int sg0_ = (q ^ sw) * 8;                                           \
    const int sg1_ = ((4 + q) ^ sw) * 8;                                     \
    half8 aA[4], aB[4], bE[4], bO[4];                                        \
    BARRIER();                                                               \
    /* R0: quad-0 operands */                                                \
    aA[0] = LDF(Ab_, 0, sg0_); aA[1] = LDF(Ab_, 1, sg0_);                    \
    aA[2] = LDF(Ab_, 2, sg0_); aA[3] = LDF(Ab_, 3, sg0_);                    \
    bE[0] = LDF(Bb_, 0, sg0_); bE[1] = LDF(Bb_, 1, sg0_);                    \
    bE[2] = LDF(Bb_, 2, sg0_); bE[3] = LDF(Bb_, 3, sg0_);                    \
    if (DO_STAGE) STAGE_ALL(SBUF);                                           \
    /* R1: quad-1 A-operands */                                              \
    aB[0] = LDF(Ab_, 4, sg0_); aB[1] = LDF(Ab_, 5, sg0_);                    \
    aB[2] = LDF(Ab_, 6, sg0_); aB[3] = LDF(Ab_, 7, sg0_);                    \
    SBAR();                                                                  \
    MQUAD(0, aA, bE)   /* lgkmcnt(4): aA,bE done; aB in flight */            \
    /* R2: quad-2 operands (aA free after MQUAD above) */                    \
    aA[0] = LDF(Ab_, 0, sg1_); aA[1] = LDF(Ab_, 1, sg1_);                    \
    aA[2] = LDF(Ab_, 2, sg1_); aA[3] = LDF(Ab_, 3, sg1_);                    \
    bO[0] = LDF(Bb_, 0, sg1_); bO[1] = LDF(Bb_, 1, sg1_);                    \
    bO[2] = LDF(Bb_, 2, sg1_); bO[3] = LDF(Bb_, 3, sg1_);                    \
    SBAR();                                                                  \
    MQUAD(4, aB, bE)   /* lgkmcnt(8) */                                      \
    /* R3: quad-3 A-operands */                                              \
    aB[0] = LDF(Ab_, 4, sg1_); aB[1] = LDF(Ab_, 5, sg1_);                    \
    aB[2] = LDF(Ab_, 6, sg1_); aB[3] = LDF(Ab_, 7, sg1_);                    \
    SBAR();                                                                  \
    MQUAD(0, aA, bO)   /* lgkmcnt(4) */                                      \
    MQUAD(4, aB, bO)   /* lgkmcnt(0) */                                      \
    if (DO_STAGE) { VMWAIT0(); }                                             \
  }

__global__ __launch_bounds__(512, 2) void gemm_fused_kernel(
    const f16* __restrict__ Xb, const f16* __restrict__ Bt,
    const float* __restrict__ h, const float* __restrict__ a_diag,
    const float* __restrict__ p_vec, const float* __restrict__ hq,
    float* __restrict__ out) {
  __shared__ __align__(16) f16 As[2][GBM * GBK];  // 2 x 32 KB
  __shared__ __align__(16) f16 Bs[2][GBN * GBK];  // 2 x 32 KB  (total 128 KB)
  const int tid = threadIdx.x;
  // 2D-aware bijective XCD swizzle: linear%8 = XCD (round-robin heuristic);
  // XCD k owns a 4(bm) x 8(bn) rectangle -> unique panel set 24MB/XCD vs 36.
  const int lin = blockIdx.x + (blockIdx.y << 4);
  const int xk = lin & 7, xr = lin >> 3;
  const int bm = ((xk & 3) << 2) | (xr & 3);
  const int bn = ((xk >> 2) << 3) | (xr >> 2);
  const int wave = tid >> 6, lane = tid & 63;
  const int wm = wave >> 2, wn = wave & 3;  // 2 x 4 wave grid

  // staging: thread covers LDS rows (tid>>3)+64*l, physical seg (tid&7);
  // global source seg is XOR-swizzled by the row (involution).
  const int srow = tid >> 3;                          // 0..63
  const int gseg = (tid & 7) ^ (srow & 7);
  const f16* ag = Xb + (size_t)(bm * GBM + srow) * HIDDEN + gseg * 8;
  const f16* bg = Bt + (size_t)(bn * GBN + srow) * HIDDEN + gseg * 8;

  f32x4 acc[8][4];
  #pragma unroll
  for (int i = 0; i < 8; i++)
    #pragma unroll
    for (int j = 0; j < 4; j++)
      acc[i][j] = (f32x4){0.f, 0.f, 0.f, 0.f};

  const int q = lane >> 4;   // k-quad within 16x16x32 fragment
  const int fm = lane & 15;  // m/n index within fragment
  const int sw = fm & 7;     // = (fragment row) & 7

  // prologue: stage tile 0 into buf 0; full drain (visibility after the
  // first TILE's barrier)
  STAGE_ALL(0);
  VMWAIT0();

  // 64 K-tiles: 31 dbuf pairs + tail pair (tile 63 stages nothing)
  #pragma unroll 1
  for (int kt2 = 0; kt2 < 31; ++kt2) {
    TILE(0, 1, 1)
    TILE(1, 0, 1)
  }
  TILE(0, 1, 1)
  TILE(1, 0, 0)

  // epilogue: C/D layout col = lane&15, row = (lane>>4)*4 + reg
  float ad[4];
  float4 pv[4];
  #pragma unroll
  for (int j = 0; j < 4; j++) {
    const int gn = bn * GBN + wn * 64 + j * 16 + fm;
    ad[j] = 1.0f + a_diag[gn];
    pv[j] = *(const float4*)(p_vec + (size_t)gn * RANK);
  }
  #pragma unroll
  for (int i = 0; i < 8; i++) {
    #pragma unroll
    for (int r = 0; r < 4; r++) {
      const size_t gb = (size_t)(bm * GBM + wm * 128 + i * 16 + q * 4 + r);
      const float4 hv = *(const float4*)(hq + gb * RANK);
      const size_t rowoff = gb * HIDDEN + bn * GBN + wn * 64 + fm;
      #pragma unroll
      for (int j = 0; j < 4; j++) {
        const size_t idx = rowoff + j * 16;
        const float hval = __builtin_nontemporal_load(&h[idx]);
        const float v = acc[i][j][r] + hval * ad[j] +
                        hv.x * pv[j].x + hv.y * pv[j].y + hv.z * pv[j].z + hv.w * pv[j].w;
        __builtin_nontemporal_store(v, &out[idx]);
      }
    }
  }
}

// ---------------------------------------------------------------------------
// Fallback (ws too small): straight f32 LDS-tiled GEMM + same epilogue.
__global__ void gemm_f32_fallback_kernel(const float* __restrict__ x, const float* __restrict__ bmat,
                                         const float* __restrict__ h, const float* __restrict__ a_diag,
                                         const float* __restrict__ p_vec, const float* __restrict__ hq,
                                         float* __restrict__ out) {
  __shared__ float As[16][64];
  __shared__ float Bs[16][68];
  const int t = threadIdx.x;
  const int bx = blockIdx.x, by = blockIdx.y;  // bx: n tile, by: m tile
  const int tm = t & 15, tn = t >> 4;
  float acc[4][4] = {{0.f}};
  for (int k0 = 0; k0 < HIDDEN; k0 += 16) {
    #pragma unroll
    for (int l = 0; l < 4; l++) {
      int idx = t + l * 256;
      int r = idx >> 4, k = idx & 15;
      As[k][r] = x[(size_t)(by * 64 + r) * HIDDEN + k0 + k];
      int kb = idx >> 6, nb = idx & 63;
      Bs[kb][nb] = bmat[(size_t)(k0 + kb) * HIDDEN + bx * 64 + nb];
    }
    __syncthreads();
    #pragma unroll
    for (int k = 0; k < 16; k++) {
      float av[4], bv[4];
      #pragma unroll
      for (int ii = 0; ii < 4; ii++) av[ii] = As[k][tm * 4 + ii];
      #pragma unroll
      for (int jj = 0; jj < 4; jj++) bv[jj] = Bs[k][tn * 4 + jj];
      #pragma unroll
      for (int ii = 0; ii < 4; ii++)
        #pragma unroll
        for (int jj = 0; jj < 4; jj++)
          acc[ii][jj] += av[ii] * bv[jj];
    }
    __syncthreads();
  }
  #pragma unroll
  for (int jj = 0; jj < 4; jj++) {
    int gn = bx * 64 + tn * 4 + jj;
    float ad = 1.0f + a_diag[gn];
    float4 pv = *(const float4*)(p_vec + (size_t)gn * RANK);
    #pragma unroll
    for (int ii = 0; ii < 4; ii++) {
      size_t gb = (size_t)(by * 64 + tm * 4 + ii);
      float4 hv = *(const float4*)(hq + gb * RANK);
      size_t idx = gb * HIDDEN + gn;
      out[idx] = acc[ii][jj] + h[idx] * ad +
                 hv.x * pv.x + hv.y * pv.y + hv.z * pv.z + hv.w * pv.w;
    }
  }
}

// ---------------------------------------------------------------------------
extern "C" void kernel_launch(void* const* d_in, const int* in_sizes, int n_in,
                              void* d_out, int out_size, void* d_ws, size_t ws_size,
                              hipStream_t stream) {
  const float* h      = (const float*)d_in[0];
  const float* x      = (const float*)d_in[1];
  const float* a_diag = (const float*)d_in[2];
  const float* p_vec  = (const float*)d_in[3];
  const float* q_vec  = (const float*)d_in[4];
  const float* b_mat  = (const float*)d_in[5];
  float* out = (float*)d_out;

  const size_t nElem = (size_t)BATCH * HIDDEN;
  const size_t hq_bytes = (size_t)BATCH * RANK * sizeof(float);       // 64 KB
  const size_t need = hq_bytes + 2 * nElem * sizeof(f16);             // + Xb + Bt

  float* hq = (float*)d_ws;
  hq_kernel<<<BATCH, 256, 0, stream>>>(h, q_vec, hq);

  if (ws_size >= need) {
    f16* Xb = (f16*)((char*)d_ws + hq_bytes);
    f16* Bt = Xb + nElem;
    cast_f16_kernel<<<nElem / 2048, 256, 0, stream>>>(x, Xb);
    transpose_cast_kernel<<<dim3(HIDDEN / 64, HIDDEN / 64), 256, 0, stream>>>(b_mat, Bt);
    gemm_fused_kernel<<<dim3(BATCH / GBM, HIDDEN / GBN), 512, 0, stream>>>(
        Xb, Bt, h, a_diag, p_vec, hq, out);
  } else {
    gemm_f32_fallback_kernel<<<dim3(HIDDEN / 64, BATCH / 64), 256, 0, stream>>>(
        x, b_mat, h, a_diag, p_vec, hq, out);
  }
}

// Round 6
// 356.394 us; speedup vs baseline: 1.0639x; 1.0056x over previous
//
#include <hip/hip_runtime.h>
#include <hip/hip_bf16.h>
#include <stdint.h>
#include <stddef.h>

#define HIDDEN 4096
#define BATCH  4096
#define RANK   4

typedef _Float16 f16;
typedef __attribute__((ext_vector_type(8))) _Float16 half8;
typedef __attribute__((ext_vector_type(4))) float f32x4;
typedef __attribute__((ext_vector_type(8))) unsigned short ushort8;

// global->LDS async copy, 16B per lane. LDS dest is wave-uniform base + lane*16.
#define ASYNC_COPY16(g, l)                                                     \
  __builtin_amdgcn_global_load_lds(                                            \
      (__attribute__((address_space(1))) void*)(g),                            \
      (__attribute__((address_space(3))) void*)(l), 16, 0, 0)

// ---------------------------------------------------------------------------
// x (f32) -> f16, 8 elems/thread
__global__ void cast_f16_kernel(const float* __restrict__ src, f16* __restrict__ dst) {
  size_t i = ((size_t)blockIdx.x * blockDim.x + threadIdx.x) * 8;
  float4 v0 = *(const float4*)(src + i);
  float4 v1 = *(const float4*)(src + i + 4);
  union { f16 h[8]; ushort8 v; } u;
  u.h[0] = (f16)v0.x; u.h[1] = (f16)v0.y; u.h[2] = (f16)v0.z; u.h[3] = (f16)v0.w;
  u.h[4] = (f16)v1.x; u.h[5] = (f16)v1.y; u.h[6] = (f16)v1.z; u.h[7] = (f16)v1.w;
  *(ushort8*)(dst + i) = u.v;
}

// ---------------------------------------------------------------------------
// b_mat [K][N] f32 -> Bt [N][K] f16, 64x64 tile transpose.
// LDS tile[n][k], 128B rows, k-seg (8 f16 = 16B) XOR-swizzled by (n>>2)&7.
__global__ void transpose_cast_kernel(const float* __restrict__ B, f16* __restrict__ Bt) {
  __shared__ __align__(16) f16 tile[64 * 64];
  const int t = threadIdx.x;
  const int bx = blockIdx.x;  // n tile
  const int by = blockIdx.y;  // k tile
  const int tx = t & 15, ty = t >> 4;
  #pragma unroll
  for (int i = 0; i < 4; i++) {
    const int k = ty + i * 16;
    float4 v = *(const float4*)(B + (size_t)(by * 64 + k) * HIDDEN + bx * 64 + tx * 4);
    f16 hv[4];
    hv[0] = (f16)v.x; hv[1] = (f16)v.y; hv[2] = (f16)v.z; hv[3] = (f16)v.w;
    #pragma unroll
    for (int c = 0; c < 4; c++) {
      const int n = tx * 4 + c;
      const int phys = (k >> 3) ^ ((n >> 2) & 7);
      tile[n * 64 + phys * 8 + (k & 7)] = hv[c];
    }
  }
  __syncthreads();
  const int wx = t & 7, wy = t >> 3;
  #pragma unroll
  for (int i = 0; i < 2; i++) {
    const int n = wy + i * 32;
    const int phys = wx ^ ((n >> 2) & 7);
    ushort8 v = *(ushort8*)&tile[n * 64 + phys * 8];
    *(ushort8*)(Bt + (size_t)(bx * 64 + n) * HIDDEN + by * 64 + wx * 8) = v;
  }
}

// ---------------------------------------------------------------------------
// hq[b][r] = sum_k h[b][k] * q[k][r]   (f32)
__global__ void hq_kernel(const float* __restrict__ h, const float* __restrict__ q,
                          float* __restrict__ hq) {
  const int b = blockIdx.x;
  const float* hrow = h + (size_t)b * HIDDEN;
  float a0 = 0.f, a1 = 0.f, a2 = 0.f, a3 = 0.f;
  for (int k = threadIdx.x; k < HIDDEN; k += 256) {
    float hv = hrow[k];
    float4 qv = *(const float4*)(q + (size_t)k * RANK);
    a0 += hv * qv.x; a1 += hv * qv.y; a2 += hv * qv.z; a3 += hv * qv.w;
  }
  #pragma unroll
  for (int off = 32; off; off >>= 1) {
    a0 += __shfl_down(a0, off, 64);
    a1 += __shfl_down(a1, off, 64);
    a2 += __shfl_down(a2, off, 64);
    a3 += __shfl_down(a3, off, 64);
  }
  __shared__ float red[4][4];
  const int wave = threadIdx.x >> 6, lane = threadIdx.x & 63;
  if (lane == 0) { red[wave][0] = a0; red[wave][1] = a1; red[wave][2] = a2; red[wave][3] = a3; }
  __syncthreads();
  if (threadIdx.x < 4) {
    float s = red[0][threadIdx.x] + red[1][threadIdx.x] + red[2][threadIdx.x] + red[3][threadIdx.x];
    hq[(size_t)b * RANK + threadIdx.x] = s;
  }
}

// ---------------------------------------------------------------------------
// Main GEMM: out = Xb(f16) @ Bt(f16)^T + h*(1+a) + hq @ p^T, f32 out.
// m201-template port: 256x256x64, 8 waves (2M x 4N), 4 phases/K-tile, each
// phase = {ds_read subtile; stage 1 unit; barrier; lgkmcnt(0); setprio(1);
// 16 MFMA; setprio(0); [counted vm wait]; barrier}.
// K-HALF staging units (16 KB each): A-kh0, B-kh0, A-kh1, B-kh1 per tile,
// one issued per phase. P0/P1 consume kh0 only, P2/P3 kh1 only ->
// counted-vmcnt is provable with 2 buffers:
//   P1-end: vmcnt(4) drains this tile's kh1 units (issued 2 phases ago in
//           the prior tile), leaves next tile's A0',B0' (4 loads) in flight.
//   P3-end: vmcnt(4) drains A0',B0', leaves A1',B1'.
// Steady state never drains (T4, m218: drain-0 on 8-phase = -38%).
// Unit LDS layout [256 rows][4 segs x 16B], phys_seg = q ^ ((row>>1)&3):
// ds_read_b128 hits each 4-bank slot with exactly 8 of 64 lanes (= wave64
// floor, conflict-free). Staging source pre-swizzled, dest linear (m104).
#define GBM 256
#define GBN 256
#define GBK 64

#define BARRIER()                                   \
  do {                                              \
    asm volatile("" ::: "memory");                  \
    __builtin_amdgcn_s_barrier();                   \
    asm volatile("" ::: "memory");                  \
  } while (0)

#define LGKM0()                                                 \
  do {                                                          \
    asm volatile("s_waitcnt lgkmcnt(0)" ::: "memory");          \
    __builtin_amdgcn_sched_barrier(0);                          \
  } while (0)

#define VMWAIT0() asm volatile("s_waitcnt vmcnt(0)" ::: "memory")
#define VMWAIT4() asm volatile("s_waitcnt vmcnt(4)" ::: "memory")
#define VMNOP()   do { } while (0)

#define RB128 ((size_t)128 * HIDDEN)  // 128-row advance, elems

// Stage one 16KB unit (2 x global_load_lds / thread). PTR = ag or bg
// (pre-swizzled per-thread source), KH = k-half, U = unit slot 0..3.
#define STAGE_U(S, U, PTR, KH)                                               \
  do {                                                                       \
    char* d_ = (char*)(&L[S][U][0]) + wave * 1024;                           \
    ASYNC_COPY16(PTR + (KH) * 32, d_);                                       \
    ASYNC_COPY16(PTR + (KH) * 32 + RB128, d_ + 8192);                        \
  } while (0)

#define RD(base, i) (*(const half8*)((base) + (i) * 512))

#define MFMA16(I0, AF, BF)                                                                    \
  __builtin_amdgcn_s_setprio(1);                                                              \
  acc[I0+0][0] = __builtin_amdgcn_mfma_f32_16x16x32_f16(AF[0], BF[0], acc[I0+0][0], 0, 0, 0); \
  acc[I0+0][1] = __builtin_amdgcn_mfma_f32_16x16x32_f16(AF[0], BF[1], acc[I0+0][1], 0, 0, 0); \
  acc[I0+0][2] = __builtin_amdgcn_mfma_f32_16x16x32_f16(AF[0], BF[2], acc[I0+0][2], 0, 0, 0); \
  acc[I0+0][3] = __builtin_amdgcn_mfma_f32_16x16x32_f16(AF[0], BF[3], acc[I0+0][3], 0, 0, 0); \
  acc[I0+1][0] = __builtin_amdgcn_mfma_f32_16x16x32_f16(AF[1], BF[0], acc[I0+1][0], 0, 0, 0); \
  acc[I0+1][1] = __builtin_amdgcn_mfma_f32_16x16x32_f16(AF[1], BF[1], acc[I0+1][1], 0, 0, 0); \
  acc[I0+1][2] = __builtin_amdgcn_mfma_f32_16x16x32_f16(AF[1], BF[2], acc[I0+1][2], 0, 0, 0); \
  acc[I0+1][3] = __builtin_amdgcn_mfma_f32_16x16x32_f16(AF[1], BF[3], acc[I0+1][3], 0, 0, 0); \
  acc[I0+2][0] = __builtin_amdgcn_mfma_f32_16x16x32_f16(AF[2], BF[0], acc[I0+2][0], 0, 0, 0); \
  acc[I0+2][1] = __builtin_amdgcn_mfma_f32_16x16x32_f16(AF[2], BF[1], acc[I0+2][1], 0, 0, 0); \
  acc[I0+2][2] = __builtin_amdgcn_mfma_f32_16x16x32_f16(AF[2], BF[2], acc[I0+2][2], 0, 0, 0); \
  acc[I0+2][3] = __builtin_amdgcn_mfma_f32_16x16x32_f16(AF[2], BF[3], acc[I0+2][3], 0, 0, 0); \
  acc[I0+3][0] = __builtin_amdgcn_mfma_f32_16x16x32_f16(AF[3], BF[0], acc[I0+3][0], 0, 0, 0); \
  acc[I0+3][1] = __builtin_amdgcn_mfma_f32_16x16x32_f16(AF[3], BF[1], acc[I0+3][1], 0, 0, 0); \
  acc[I0+3][2] = __builtin_amdgcn_mfma_f32_16x16x32_f16(AF[3], BF[2], acc[I0+3][2], 0, 0, 0); \
  acc[I0+3][3] = __builtin_amdgcn_mfma_f32_16x16x32_f16(AF[3], BF[3], acc[I0+3][3], 0, 0, 0); \
  __builtin_amdgcn_s_setprio(0);

// One K-tile = 4 phases. BUF consumed, SBUF staged (next tile).
// W1/W3: counted waits (VMWAIT4 steady; tail: VMWAIT0 / none).
#define TILE8(BUF, SBUF, DO_STAGE, W1, W3)                                   \
  {                                                                          \
    const f16* A0_ = &L[BUF][0][0] + (wm * 128 + fm) * 32 + pseg * 8;        \
    const f16* B0_ = &L[BUF][1][0] + (wn * 64 + fm) * 32 + pseg * 8;         \
    const f16* A1_ = &L[BUF][2][0] + (wm * 128 + fm) * 32 + pseg * 8;        \
    const f16* B1_ = &L[BUF][3][0] + (wn * 64 + fm) * 32 + pseg * 8;         \
    half8 aA[4], bB[4];                                                      \
    /* P0: kk0, rows 0-3 x cols 0-3 */                                       \
    aA[0] = RD(A0_, 0); aA[1] = RD(A0_, 1);                                  \
    aA[2] = RD(A0_, 2); aA[3] = RD(A0_, 3);                                  \
    bB[0] = RD(B0_, 0); bB[1] = RD(B0_, 1);                                  \
    bB[2] = RD(B0_, 2); bB[3] = RD(B0_, 3);                                  \
    if (DO_STAGE) STAGE_U(SBUF, 0, ag, 0);                                   \
    BARRIER();                                                               \
    LGKM0();                                                                 \
    MFMA16(0, aA, bB)                                                        \
    BARRIER();                                                               \
    /* P1: kk0, rows 4-7 (bB reused) */                                      \
    aA[0] = RD(A0_, 4); aA[1] = RD(A0_, 5);                                  \
    aA[2] = RD(A0_, 6); aA[3] = RD(A0_, 7);                                  \
    if (DO_STAGE) STAGE_U(SBUF, 1, bg, 0);                                   \
    BARRIER();                                                               \
    LGKM0();                                                                 \
    MFMA16(4, aA, bB)                                                        \
    W1;                                                                      \
    BARRIER();                                                               \
    /* P2: kk1, rows 0-3 x cols 0-3 */                                       \
    aA[0] = RD(A1_, 0); aA[1] = RD(A1_, 1);                                  \
    aA[2] = RD(A1_, 2); aA[3] = RD(A1_, 3);                                  \
    bB[0] = RD(B1_, 0); bB[1] = RD(B1_, 1);                                  \
    bB[2] = RD(B1_, 2); bB[3] = RD(B1_, 3);                                  \
    if (DO_STAGE) STAGE_U(SBUF, 2, ag, 1);                                   \
    BARRIER();                                                               \
    LGKM0();                                                                 \
    MFMA16(0, aA, bB)                                                        \
    BARRIER();                                                               \
    /* P3: kk1, rows 4-7 */                                                  \
    aA[0] = RD(A1_, 4); aA[1] = RD(A1_, 5);                                  \
    aA[2] = RD(A1_, 6); aA[3] = RD(A1_, 7);                                  \
    if (DO_STAGE) { STAGE_U(SBUF, 3, bg, 1); ag += GBK; bg += GBK; }         \
    BARRIER();                                                               \
    LGKM0();                                                                 \
    MFMA16(4, aA, bB)                                                        \
    W3;                                                                      \
    BARRIER();                                                               \
  }

__global__ __launch_bounds__(512, 2) void gemm_fused_kernel(
    const f16* __restrict__ Xb, const f16* __restrict__ Bt,
    const float* __restrict__ h, const float* __restrict__ a_diag,
    const float* __restrict__ p_vec, const float* __restrict__ hq,
    float* __restrict__ out) {
  // [buf][unit][256 rows x 32 k]; units: 0=A-kh0 1=B-kh0 2=A-kh1 3=B-kh1
  __shared__ __align__(16) f16 L[2][4][256 * 32];  // 128 KB
  const int tid = threadIdx.x;
  // 2D-aware bijective XCD swizzle (round 5: FETCH 182->133 GB).
  const int lin = blockIdx.x + (blockIdx.y << 4);
  const int xk = lin & 7, xr = lin >> 3;
  const int bm = ((xk & 3) << 2) | (xr & 3);
  const int bn = ((xk >> 2) << 3) | (xr >> 2);
  const int wave = tid >> 6, lane = tid & 63;
  const int wm = wave >> 2, wn = wave & 3;  // 2 x 4 wave grid

  // staging: thread covers unit rows (tid>>2)+128*l, phys seg (tid&3);
  // source seg pre-swizzled: gseg = (tid&3) ^ ((tid>>3)&3)  (involution
  // matching the read-side phys_seg = q ^ ((row>>1)&3)).
  const int srow = tid >> 2;                          // 0..127
  const int gseg = (tid & 3) ^ ((tid >> 3) & 3);
  const f16* ag = Xb + (size_t)(bm * GBM + srow) * HIDDEN + gseg * 8;
  const f16* bg = Bt + (size_t)(bn * GBN + srow) * HIDDEN + gseg * 8;

  f32x4 acc[8][4];
  #pragma unroll
  for (int i = 0; i < 8; i++)
    #pragma unroll
    for (int j = 0; j < 4; j++)
      acc[i][j] = (f32x4){0.f, 0.f, 0.f, 0.f};

  const int q = lane >> 4;   // k-quad within 16x16x32 fragment
  const int fm = lane & 15;  // m/n index within fragment
  const int pseg = q ^ ((fm >> 1) & 3);  // swizzled LDS seg for frag reads

  // prologue: stage tile 0 (4 units) into buf 0; vmcnt(4) -> kh0 resident,
  // kh1 units (4 loads) still in flight (drained at tile-0 P1-end).
  STAGE_U(0, 0, ag, 0);
  STAGE_U(0, 1, bg, 0);
  STAGE_U(0, 2, ag, 1);
  STAGE_U(0, 3, bg, 1);
  ag += GBK; bg += GBK;
  VMWAIT4();
  BARRIER();

  // 64 K-tiles: 31 dbuf pairs + tile 62 (stages 63) + tile 63 (tail)
  #pragma unroll 1
  for (int kt2 = 0; kt2 < 31; ++kt2) {
    TILE8(0, 1, 1, VMWAIT4(), VMWAIT4())
    TILE8(1, 0, 1, VMWAIT4(), VMWAIT4())
  }
  TILE8(0, 1, 1, VMWAIT4(), VMWAIT4())
  TILE8(1, 0, 0, VMWAIT0(), VMNOP())

  // epilogue: C/D layout col = lane&15, row = (lane>>4)*4 + reg
  float ad[4];
  float4 pv[4];
  #pragma unroll
  for (int j = 0; j < 4; j++) {
    const int gn = bn * GBN + wn * 64 + j * 16 + fm;
    ad[j] = 1.0f + a_diag[gn];
    pv[j] = *(const float4*)(p_vec + (size_t)gn * RANK);
  }
  #pragma unroll
  for (int i = 0; i < 8; i++) {
    #pragma unroll
    for (int r = 0; r < 4; r++) {
      const size_t gb = (size_t)(bm * GBM + wm * 128 + i * 16 + q * 4 + r);
      const float4 hv = *(const float4*)(hq + gb * RANK);
      const size_t rowoff = gb * HIDDEN + bn * GBN + wn * 64 + fm;
      #pragma unroll
      for (int j = 0; j < 4; j++) {
        const size_t idx = rowoff + j * 16;
        const float hval = __builtin_nontemporal_load(&h[idx]);
        const float v = acc[i][j][r] + hval * ad[j] +
                        hv.x * pv[j].x + hv.y * pv[j].y + hv.z * pv[j].z + hv.w * pv[j].w;
        __builtin_nontemporal_store(v, &out[idx]);
      }
    }
  }
}

// ---------------------------------------------------------------------------
// Fallback (ws too small): straight f32 LDS-tiled GEMM + same epilogue.
__global__ void gemm_f32_fallback_kernel(const float* __restrict__ x, const float* __restrict__ bmat,
                                         const float* __restrict__ h, const float* __restrict__ a_diag,
                                         const float* __restrict__ p_vec, const float* __restrict__ hq,
                                         float* __restrict__ out) {
  __shared__ float As[16][64];
  __shared__ float Bs[16][68];
  const int t = threadIdx.x;
  const int bx = blockIdx.x, by = blockIdx.y;  // bx: n tile, by: m tile
  const int tm = t & 15, tn = t >> 4;
  float acc[4][4] = {{0.f}};
  for (int k0 = 0; k0 < HIDDEN; k0 += 16) {
    #pragma unroll
    for (int l = 0; l < 4; l++) {
      int idx = t + l * 256;
      int r = idx >> 4, k = idx & 15;
      As[k][r] = x[(size_t)(by * 64 + r) * HIDDEN + k0 + k];
      int kb = idx >> 6, nb = idx & 63;
      Bs[kb][nb] = bmat[(size_t)(k0 + kb) * HIDDEN + bx * 64 + nb];
    }
    __syncthreads();
    #pragma unroll
    for (int k = 0; k < 16; k++) {
      float av[4], bv[4];
      #pragma unroll
      for (int ii = 0; ii < 4; ii++) av[ii] = As[k][tm * 4 + ii];
      #pragma unroll
      for (int jj = 0; jj < 4; jj++) bv[jj] = Bs[k][tn * 4 + jj];
      #pragma unroll
      for (int ii = 0; ii < 4; ii++)
        #pragma unroll
        for (int jj = 0; jj < 4; jj++)
          acc[ii][jj] += av[ii] * bv[jj];
    }
    __syncthreads();
  }
  #pragma unroll
  for (int jj = 0; jj < 4; jj++) {
    int gn = bx * 64 + tn * 4 + jj;
    float ad = 1.0f + a_diag[gn];
    float4 pv = *(const float4*)(p_vec + (size_t)gn * RANK);
    #pragma unroll
    for (int ii = 0; ii < 4; ii++) {
      size_t gb = (size_t)(by * 64 + tm * 4 + ii);
      float4 hv = *(const float4*)(hq + gb * RANK);
      size_t idx = gb * HIDDEN + gn;
      out[idx] = acc[ii][jj] + h[idx] * ad +
                 hv.x * pv.x + hv.y * pv.y + hv.z * pv.z + hv.w * pv.w;
    }
  }
}

// ---------------------------------------------------------------------------
extern "C" void kernel_launch(void* const* d_in, const int* in_sizes, int n_in,
                              void* d_out, int out_size, void* d_ws, size_t ws_size,
                              hipStream_t stream) {
  const float* h      = (const float*)d_in[0];
  const float* x      = (const float*)d_in[1];
  const float* a_diag = (const float*)d_in[2];
  const float* p_vec  = (const float*)d_in[3];
  const float* q_vec  = (const float*)d_in[4];
  const float* b_mat  = (const float*)d_in[5];
  float* out = (float*)d_out;

  const size_t nElem = (size_t)BATCH * HIDDEN;
  const size_t hq_bytes = (size_t)BATCH * RANK * sizeof(float);       // 64 KB
  const size_t need = hq_bytes + 2 * nElem * sizeof(f16);             // + Xb + Bt

  float* hq = (float*)d_ws;
  hq_kernel<<<BATCH, 256, 0, stream>>>(h, q_vec, hq);

  if (ws_size >= need) {
    f16* Xb = (f16*)((char*)d_ws + hq_bytes);
    f16* Bt = Xb + nElem;
    cast_f16_kernel<<<nElem / 2048, 256, 0, stream>>>(x, Xb);
    transpose_cast_kernel<<<dim3(HIDDEN / 64, HIDDEN / 64), 256, 0, stream>>>(b_mat, Bt);
    gemm_fused_kernel<<<dim3(BATCH / GBM, HIDDEN / GBN), 512, 0, stream>>>(
        Xb, Bt, h, a_diag, p_vec, hq, out);
  } else {
    gemm_f32_fallback_kernel<<<dim3(HIDDEN / 64, BATCH / 64), 256, 0, stream>>>(
        x, b_mat, h, a_diag, p_vec, hq, out);
  }
}